// Round 14
// baseline (479.317 us; speedup 1.0000x reference)
//
#include <hip/hip_runtime.h>

#define KNN 16
static constexpr int BB = 16;
static constexpr float LEAK = 0.2f;
static constexpr float EPSV = 1e-5f;
typedef unsigned long long u64;

// ---------------- branch-free bitonic top-16 primitives -------------------
__device__ __forceinline__ void ce_asc(u64 &a, u64 &b) {
  u64 x = a, y = b; bool sw = y < x; a = sw ? y : x; b = sw ? x : y;
}
__device__ __forceinline__ void ce_desc(u64 &a, u64 &b) {
  u64 x = a, y = b; bool sw = x < y; a = sw ? y : x; b = sw ? x : y;
}
__device__ __forceinline__ void bitonic_sort16(u64 *T) {
#pragma unroll
  for (int k = 2; k <= 16; k <<= 1) {
#pragma unroll
    for (int j = k >> 1; j > 0; j >>= 1) {
#pragma unroll
      for (int i = 0; i < 16; ++i) {
        int l = i ^ j;
        if (l > i) {
          if ((i & k) == 0) ce_asc(T[i], T[l]); else ce_desc(T[i], T[l]);
        }
      }
    }
  }
}
__device__ __forceinline__ void merge_sorted16(u64 *R, const u64 *T) {
#pragma unroll
  for (int i = 0; i < 16; ++i) {
    u64 t = T[15 - i];
    R[i] = t < R[i] ? t : R[i];
  }
#pragma unroll
  for (int j = 8; j > 0; j >>= 1) {
#pragma unroll
    for (int i = 0; i < 16; ++i) {
      int l = i ^ j;
      if (l > i) ce_asc(R[i], R[l]);
    }
  }
}
template<int KC>
__device__ __forceinline__ void merge_row(const u64* __restrict__ p, u64* R) {
#pragma unroll
  for (int s = 0; s < 16; ++s) R[s] = p[s];
#pragma unroll
  for (int c = 1; c < KC; ++c) {
    u64 T[16];
#pragma unroll
    for (int s = 0; s < 16; ++s) T[s] = p[(size_t)c*KNN + s];
    merge_sorted16(R, T);
  }
}

// ---------------- device: f0 = w_in @ coor + b_in -------------------------
__device__ __forceinline__ void f0_dev(const float* __restrict__ x,
    const float* __restrict__ w_in, const float* __restrict__ b_in,
    float* __restrict__ f0, int bid) {
  int i = bid * 256 + threadIdx.x;
  float px = x[i*3+0], py = x[i*3+1], pz = x[i*3+2];
#pragma unroll
  for (int o = 0; o < 8; ++o) {
    f0[i*8+o] = w_in[o*3+0]*px + w_in[o*3+1]*py + w_in[o*3+2]*pz + b_in[o];
  }
}

// ---------------- device: kNN split-K partial top-16 ----------------------
__device__ void knn_part_dev(const float* __restrict__ qxyz, int Nq,
    const float* __restrict__ kxyz, int Nk, int KC, u64* __restrict__ part,
    char* sm, int bid) {
  float4* keys = (float4*)sm;
  int nqb = (Nq + 255) >> 8;
  int c  = bid % KC;
  int qb = (bid / KC) % nqb;
  int b  = bid / (KC * nqb);
  int nkc = Nk / KC;
  int kbase = c * nkc;
  for (int j = threadIdx.x; j < nkc; j += 256) {
    const float* kp = kxyz + (size_t)(b*Nk + kbase + j)*3;
    float kx = kp[0], ky = kp[1], kz = kp[2];
    keys[j] = make_float4(kx, ky, kz, kx*kx + ky*ky + kz*kz);
  }
  __syncthreads();
  int q = (qb << 8) + threadIdx.x;
  if (q >= Nq) return;
  const float* qp = qxyz + (size_t)(b*Nq + q)*3;
  float qx = qp[0], qy = qp[1], qz = qp[2];
  float q2 = qx*qx + qy*qy + qz*qz;
  u64 R[16];
#pragma unroll
  for (int s = 0; s < 16; ++s) R[s] = 0xFFFFFFFFFFFFFFFFull;
  for (int j0 = 0; j0 < nkc; j0 += 16) {
    u64 T[16];
#pragma unroll
    for (int u = 0; u < 16; ++u) {
      float4 kk = keys[j0 + u];
      float qk = qx*kk.x + qy*kk.y + qz*kk.z;
      float d2 = q2 + kk.w - 2.0f*qk;
      int bb = __float_as_int(d2);
      unsigned k32 = (unsigned)bb ^ (unsigned)((bb >> 31) | 0x80000000);
      T[u] = ((u64)k32 << 32) | (unsigned)(kbase + j0 + u);
    }
    bitonic_sort16(T);
    merge_sorted16(R, T);
  }
  u64* op = part + ((size_t)(b*Nq + q)*KC + c)*KNN;
#pragma unroll
  for (int s = 0; s < KNN; ++s) op[s] = R[s];
}

// ---------------- device: 4-wave FPS (fps1), f32 DPP reduce ---------------
__device__ __forceinline__ u64 fps_max64(u64 a, u64 b) { return a > b ? a : b; }
template<int CTRL>
__device__ __forceinline__ float fps_dpp_fmax(float v) {
  int nb = __builtin_amdgcn_update_dpp(0, __float_as_int(v), CTRL, 0xF, 0xF, false);
  return fmaxf(v, __int_as_float(nb));   // dl >= 0, 0-fill harmless
}
__device__ __forceinline__ float rl_f(float v, int l) {
  return __int_as_float(__builtin_amdgcn_readlane(__float_as_int(v), l));
}
template<int P, bool SAVE>
__device__ void fps_seg_dev(const float* __restrict__ xyz, int np,
    int t0, int t1, int* __restrict__ fidx,
    float* __restrict__ g_dl, int* __restrict__ g_far,
    float* __restrict__ cq, char* sm, int b) {
  constexpr int NN = P * 256;
  float4* sc  = (float4*)sm;                     // [NN]
  int* s_fid  = (int*)(sm + NN*16);              // [512]
  u64* s_key  = (u64*)(sm + NN*16 + 2048);       // [2][4]
  __builtin_amdgcn_s_setprio(1);
  int tid = threadIdx.x;
  int w = tid >> 6, lw = tid & 63;
  float px[P], py[P], pz[P], dl[P];
#pragma unroll
  for (int i = 0; i < P; ++i) {
    int p = tid * P + i;
    const float* pp = xyz + (size_t)(b*NN + p)*3;
    px[i] = pp[0]; py[i] = pp[1]; pz[i] = pp[2];
    sc[p] = make_float4(px[i], py[i], pz[i], 0.f);
  }
  int far;
  if (t0 == 0) {
#pragma unroll
    for (int i = 0; i < P; ++i) dl[i] = 1e10f;
    far = 0;
  } else {
#pragma unroll
    for (int i = 0; i < P; ++i) dl[i] = g_dl[b*NN + tid*P + i];
    far = g_far[b];
  }
  __syncthreads();
  for (int t = t0; t < t1; ++t) {
    if (tid == 0) s_fid[t] = far;
    float4 cc = sc[far];                         // uniform LDS broadcast
#pragma unroll
    for (int i = 0; i < P; ++i) {
      float dx = __fsub_rn(px[i], cc.x);
      float dy = __fsub_rn(py[i], cc.y);
      float dz = __fsub_rn(pz[i], cc.z);
      float d = __fadd_rn(__fadd_rn(__fmul_rn(dx,dx), __fmul_rn(dy,dy)), __fmul_rn(dz,dz));
      dl[i] = fminf(dl[i], d);
    }
    float m[P];
#pragma unroll
    for (int i = 0; i < P; ++i) m[i] = dl[i];
#pragma unroll
    for (int st = P/2; st > 0; st >>= 1) {
#pragma unroll
      for (int i = 0; i < P; ++i) if (i < st) m[i] = fmaxf(m[i], m[i + st]);
    }
    float lmax = m[0];
    unsigned msk = 0u;
#pragma unroll
    for (int i = 0; i < P; ++i) msk |= (dl[i] == lmax) ? (1u << i) : 0u;
    int lidx = tid * P + __builtin_ctz(msk);     // lowest p in this thread
    float v = lmax;
    v = fps_dpp_fmax<0x111>(v);  // row_shr:1
    v = fps_dpp_fmax<0x112>(v);  // row_shr:2
    v = fps_dpp_fmax<0x114>(v);  // row_shr:4
    v = fps_dpp_fmax<0x118>(v);  // row_shr:8
    v = fps_dpp_fmax<0x142>(v);  // row_bcast:15
    v = fps_dpp_fmax<0x143>(v);  // row_bcast:31
    float wmax = rl_f(v, 63);
    u64 bal = __ballot(lmax == wmax);
    int l0 = __ffsll((unsigned long long)bal) - 1;
    int wp = __builtin_amdgcn_readlane(lidx, l0);
    int buf = t & 1;
    if (lw == 0)
      s_key[buf*4 + w] = ((u64)__float_as_uint(wmax) << 32) | (unsigned)(~wp);
    __syncthreads();
    u64 best = s_key[buf*4 + 0];
    best = fps_max64(best, s_key[buf*4 + 1]);
    best = fps_max64(best, s_key[buf*4 + 2]);
    best = fps_max64(best, s_key[buf*4 + 3]);
    far = (int)(~(unsigned)(best & 0xFFFFFFFFull));
  }
  // batched fidx writes (s_fid visible: last iteration ended in a barrier)
  for (int t = t0 + tid; t < t1; t += 256) fidx[b*np + t] = s_fid[t];
  if constexpr (SAVE) {
#pragma unroll
    for (int i = 0; i < P; ++i) g_dl[b*NN + tid*P + i] = dl[i];
    if (tid == 0) g_far[b] = far;
  } else {
    for (int j = tid; j < np; j += 256) {
      int p = (j >= t0) ? s_fid[j] : fidx[b*np + j];
      float4 c = sc[p];
      float* cp = cq + (size_t)(b*np + j)*3;
      cp[0] = c.x; cp[1] = c.y; cp[2] = c.z;
    }
  }
  __builtin_amdgcn_s_setprio(0);
}

// ---------------- device: SINGLE-WAVE FPS (fps2) — zero barriers ----------
template<int P, bool SAVE>
__device__ void fps2_wave_dev(const float* __restrict__ xyz, int np,
    int t0, int t1, int* __restrict__ fidx,
    float* __restrict__ g_dl, int* __restrict__ g_far,
    float* __restrict__ cq, char* sm, int b) {
  constexpr int NN = P * 64;
  int* s_fid = (int*)sm;                         // [np]
  __builtin_amdgcn_s_setprio(1);
  int l = threadIdx.x;                           // 0..63
  float px[P], py[P], pz[P], dl[P];
#pragma unroll
  for (int i = 0; i < P; ++i) {
    int p = l * P + i;
    const float* pp = xyz + (size_t)(b*NN + p)*3;
    px[i] = pp[0]; py[i] = pp[1]; pz[i] = pp[2];
  }
  int far;
  if (t0 == 0) {
#pragma unroll
    for (int i = 0; i < P; ++i) dl[i] = 1e10f;
    far = 0;
  } else {
#pragma unroll
    for (int i = 0; i < P; ++i) dl[i] = g_dl[b*NN + l*P + i];
    far = g_far[b];
  }
  const float* fp = xyz + (size_t)(b*NN + far)*3;
  float ccx = fp[0], ccy = fp[1], ccz = fp[2];
  for (int t = t0; t < t1; ++t) {
    if (l == 0) s_fid[t] = far;
#pragma unroll
    for (int i = 0; i < P; ++i) {
      float dx = __fsub_rn(px[i], ccx);
      float dy = __fsub_rn(py[i], ccy);
      float dz = __fsub_rn(pz[i], ccz);
      float d = __fadd_rn(__fadd_rn(__fmul_rn(dx,dx), __fmul_rn(dy,dy)), __fmul_rn(dz,dz));
      dl[i] = fminf(dl[i], d);
    }
    float m[P];
#pragma unroll
    for (int i = 0; i < P; ++i) m[i] = dl[i];
#pragma unroll
    for (int st = P/2; st > 0; st >>= 1) {
#pragma unroll
      for (int i = 0; i < P; ++i) if (i < st) m[i] = fmaxf(m[i], m[i + st]);
    }
    float lmax = m[0];
    unsigned msk = 0u;
#pragma unroll
    for (int i = 0; i < P; ++i) msk |= (dl[i] == lmax) ? (1u << i) : 0u;
    int ib = __builtin_ctz(msk);
    int lidx = l * P + ib;
    float cxl = px[P-1], cyl = py[P-1], czl = pz[P-1];
#pragma unroll
    for (int i = P-1; i >= 0; --i) {
      bool tk = (msk >> i) & 1u;
      cxl = tk ? px[i] : cxl;
      cyl = tk ? py[i] : cyl;
      czl = tk ? pz[i] : czl;
    }
    float v = lmax;
    v = fps_dpp_fmax<0x111>(v);
    v = fps_dpp_fmax<0x112>(v);
    v = fps_dpp_fmax<0x114>(v);
    v = fps_dpp_fmax<0x118>(v);
    v = fps_dpp_fmax<0x142>(v);
    v = fps_dpp_fmax<0x143>(v);
    float wmax = rl_f(v, 63);
    u64 bal = __ballot(lmax == wmax);
    int l0 = __ffsll((unsigned long long)bal) - 1;   // lowest lane = lowest p
    far = __builtin_amdgcn_readlane(lidx, l0);
    ccx = rl_f(cxl, l0); ccy = rl_f(cyl, l0); ccz = rl_f(czl, l0);
  }
  for (int t = t0 + l; t < t1; t += 64) fidx[b*np + t] = s_fid[t];
  if constexpr (SAVE) {
#pragma unroll
    for (int i = 0; i < P; ++i) g_dl[b*NN + l*P + i] = dl[i];
    if (l == 0) g_far[b] = far;
  } else {
    for (int j = l; j < np; j += 64) {
      int p = (j >= t0) ? s_fid[j] : fidx[b*np + j];
      const float* sp = xyz + (size_t)(b*NN + p)*3;
      float* cp = cq + (size_t)(b*np + j)*3;
      cp[0] = sp[0]; cp[1] = sp[1]; cp[2] = sp[2];
    }
  }
  __builtin_amdgcn_s_setprio(0);
}

// ---------------- device: conv + fused GN stats + minmax over k ----------
// fq rows come from fq[b*Nfq + (qmap? qmap[b*Nq+q] : q)] — qmap folds the
// FPS gather into the conv load (no fq1/fq2 buffers).
template<int C, int O, int QB, int KC, int NB>
__device__ void conv_dev(const float* __restrict__ fsrc, int Nsrc,
    const float* __restrict__ fq, int Nfq, const int* __restrict__ qmap,
    int Nq, const u64* __restrict__ part,
    const float* __restrict__ w, float* __restrict__ ym, float* __restrict__ yn,
    double2* __restrict__ pp1, char* sm, int bid) {
  constexpr int Og = O / 4;
  constexpr int C4 = C / 4;
  double* rs  = (double*)sm;                    // [256]
  double* rs2 = rs + 256;                       // [256]
  float* ft   = (float*)(sm + 4096);            // [QB][KNN][C]
  float* fqs  = ft + QB*KNN*C;                  // [QB][C]
  int* s_idx  = (int*)(fqs + QB*C);             // [QB][KNN]
  int tid = threadIdx.x;
  int chunk = bid % NB;
  int b = bid / NB;
  int q0 = chunk * QB;
  if (tid < QB) {
    const u64* p = part + (size_t)(b*Nq + q0 + tid)*KC*KNN;
    u64 R[16];
    merge_row<KC>(p, R);
#pragma unroll
    for (int s = 0; s < 16; ++s) s_idx[tid*KNN + s] = (int)(unsigned)(R[s] & 0xFFFFFFFFu);
  } else if (tid >= 64 && tid < 64 + QB*C4) {
    int t = tid - 64;
    int ql = t / C4, c4 = t % C4;
    int q = q0 + ql;
    int sq = qmap ? qmap[b*Nq + q] : q;
    ((float4*)&fqs[ql*C])[c4] = ((const float4*)(fq + ((size_t)b*Nfq + sq)*C))[c4];
  }
  __syncthreads();
  for (int v = tid; v < QB*KNN*C4; v += 256) {
    int row = v / C4, c4 = v % C4;
    int ql = row / KNN, k = row % KNN;
    int src = s_idx[ql*KNN + k];
    ((float4*)&ft[(ql*KNN + k)*C])[c4] = ((const float4*)(fsrc + (size_t)(b*Nsrc + src)*C))[c4];
  }
  __syncthreads();
  int ql = tid / O, o = tid % O;
  float4 wr4[C4];
  float bs = 0.f;
  const float4* wp4 = (const float4*)(w + (size_t)o*2*C);
#pragma unroll
  for (int c4 = 0; c4 < C4; ++c4) {
    float4 lo = wp4[c4], hi = wp4[C4 + c4];
    float4 fv = ((const float4*)&fqs[ql*C])[c4];
    bs += (hi.x - lo.x) * fv.x;
    bs += (hi.y - lo.y) * fv.y;
    bs += (hi.z - lo.z) * fv.z;
    bs += (hi.w - lo.w) * fv.w;
    wr4[c4] = lo;
  }
  float mx = -3.4e38f, mn = 3.4e38f;
  double s = 0.0, s2 = 0.0;
  for (int k = 0; k < KNN; ++k) {
    float acc = bs;
    const float4* fv = (const float4*)&ft[(ql*KNN + k)*C];
#pragma unroll
    for (int c4 = 0; c4 < C4; ++c4) {
      float4 v = fv[c4];
      acc += wr4[c4].x*v.x; acc += wr4[c4].y*v.y;
      acc += wr4[c4].z*v.z; acc += wr4[c4].w*v.w;
    }
    mx = fmaxf(mx, acc);
    mn = fminf(mn, acc);
    s += acc;
    s2 += (double)acc * (double)acc;
  }
  size_t oidx = (size_t)(b*Nq + q0 + ql)*O + o;
  ym[oidx] = mx;
  yn[oidx] = mn;
  rs[tid] = s; rs2[tid] = s2;
  __syncthreads();
#pragma unroll
  for (int st = QB/2; st > 0; st >>= 1) {
    if (ql < st) { rs[tid] += rs[tid + st*O]; rs2[tid] += rs2[tid + st*O]; }
    __syncthreads();
  }
#pragma unroll
  for (int st = Og/2; st > 0; st >>= 1) {
    if (tid < O && (o % Og) < st) { rs[tid] += rs[tid + st]; rs2[tid] += rs2[tid + st]; }
    __syncthreads();
  }
  if (tid < O && (o % Og) == 0) {
    int g = o / Og;
    pp1[((size_t)b*NB + chunk)*4 + g] = make_double2(rs[tid], rs2[tid]);
  }
}

// ---------------- device: finalize (GN + lrelu from minmax) ---------------
template<int O, int NB, int FCH, int NQ>
__device__ void fin_dev(const float* __restrict__ ym, const float* __restrict__ yn,
    const double2* __restrict__ pp1, const float* __restrict__ gamma,
    const float* __restrict__ beta, float* __restrict__ fout, char* sm, int bid) {
  constexpr int Og = O / 4;
  double* red  = (double*)sm;                   // [64]
  double* red2 = red + 64;                      // [64]
  float* s_mu  = (float*)(red2 + 64);           // [4]
  float* s_rsv = s_mu + 4;                      // [4]
  int tid = threadIdx.x;
  int b = bid / FCH;
  int f = bid % FCH;
  if (tid < 64) {
    int g = tid >> 4, j = tid & 15;
    double s = 0.0, s2 = 0.0;
    for (int c = j; c < NB; c += 16) {
      double2 v = pp1[((size_t)b*NB + c)*4 + g];
      s += v.x; s2 += v.y;
    }
    red[tid] = s; red2[tid] = s2;
  }
  __syncthreads();
#pragma unroll
  for (int st = 8; st > 0; st >>= 1) {
    if (tid < 64 && (tid & 15) < st) { red[tid] += red[tid+st]; red2[tid] += red2[tid+st]; }
    __syncthreads();
  }
  if (tid < 4) {
    double cnt = (double)Og * (double)NQ * (double)KNN;
    double mu = red[tid*16] / cnt;
    double var = red2[tid*16] / cnt - mu*mu;
    s_mu[tid] = (float)mu;
    s_rsv[tid] = 1.0f / sqrtf((float)var + EPSV);
  }
  __syncthreads();
  constexpr int PER = NQ * O / FCH;
  int e0 = f * PER;
  for (int e = e0 + tid; e < e0 + PER; e += 256) {
    int q = e / O, o = e % O;
    int g = o / Og;
    size_t idx = (size_t)(b*NQ + q)*O + o;
    float ga = gamma[o], be = beta[o];
    float ysel = (ga >= 0.f) ? ym[idx] : yn[idx];
    float xn = (ysel - s_mu[g]) * s_rsv[g];
    float yv = xn*ga + be;
    yv = yv > 0.f ? yv : LEAK*yv;
    fout[idx] = yv;
  }
}

// ---------------- dispatch wrappers (dynamic shared) ----------------------
__global__ __launch_bounds__(256) void fusedA_kernel(const float* __restrict__ x,
    const float* __restrict__ w_in, const float* __restrict__ b_in,
    float* __restrict__ f0, u64* __restrict__ part, int* __restrict__ fidx1,
    float* __restrict__ g_dl, int* __restrict__ g_far) {
  extern __shared__ char sm[];
  int bid = blockIdx.x;
  if (bid < 16)        fps_seg_dev<8,true>(x, 512, 0, 280, fidx1, g_dl, g_far, nullptr, sm, bid);
  else if (bid < 1040) knn_part_dev(x, 2048, x, 2048, 8, part, sm, bid - 16);
  else                 f0_dev(x, w_in, b_in, f0, bid - 1040);
}

__global__ __launch_bounds__(256) void conv1_kernel(const float* __restrict__ x,
    int* __restrict__ fidx1, float* __restrict__ g_dl, int* __restrict__ g_far,
    const float* __restrict__ f0, const u64* __restrict__ part,
    const float* __restrict__ w1, float* __restrict__ ym, float* __restrict__ yn,
    double2* __restrict__ pp1) {
  extern __shared__ char sm[];
  int bid = blockIdx.x;
  if (bid < 16) fps_seg_dev<8,true>(x, 512, 280, 460, fidx1, g_dl, g_far, nullptr, sm, bid);
  else          conv_dev<8,32,8,8,256>(f0, 2048, f0, 2048, nullptr, 2048, part, w1, ym, yn, pp1, sm, bid - 16);
}

__global__ __launch_bounds__(256) void fin1_kernel(const float* __restrict__ x,
    int* __restrict__ fidx1, float* __restrict__ g_dl, int* __restrict__ g_far,
    float* __restrict__ cq1,
    const float* __restrict__ ym, const float* __restrict__ yn,
    const double2* __restrict__ pp1, const float* __restrict__ g1,
    const float* __restrict__ be1, float* __restrict__ f1) {
  extern __shared__ char sm[];
  int bid = blockIdx.x;
  if (bid < 16) fps_seg_dev<8,false>(x, 512, 460, 512, fidx1, g_dl, g_far, cq1, sm, bid);
  else          fin_dev<32,256,32,2048>(ym, yn, pp1, g1, be1, f1, sm, bid - 16);
}

__global__ __launch_bounds__(256) void fusedB_kernel(const float* __restrict__ cq1,
    const float* __restrict__ x, u64* __restrict__ part2, u64* __restrict__ part3,
    int* __restrict__ fidx2, float* __restrict__ g_dl, int* __restrict__ g_far) {
  extern __shared__ char sm[];
  int bid = blockIdx.x;
  if (bid < 16) {
    if (threadIdx.x < 64)
      fps2_wave_dev<8,true>(cq1, 128, 0, 100, fidx2, g_dl, g_far, nullptr, sm, bid);
  } else if (bid < 272) {
    knn_part_dev(cq1, 512, x, 2048, 8, part2, sm, bid - 16);
  } else {
    knn_part_dev(cq1, 512, cq1, 512, 8, part3, sm, bid - 272);
  }
}

__global__ __launch_bounds__(256) void conv2_kernel(const float* __restrict__ cq1,
    int* __restrict__ fidx2, float* __restrict__ g_dl, int* __restrict__ g_far,
    float* __restrict__ cq2,
    const float* __restrict__ f1, const int* __restrict__ fidx1,
    const u64* __restrict__ part2, const float* __restrict__ w2,
    float* __restrict__ ym, float* __restrict__ yn, double2* __restrict__ pp1) {
  extern __shared__ char sm[];
  int bid = blockIdx.x;
  if (bid < 16) {
    if (threadIdx.x < 64)
      fps2_wave_dev<8,false>(cq1, 128, 100, 128, fidx2, g_dl, g_far, cq2, sm, bid);
  }
  else conv_dev<32,64,4,8,128>(f1, 2048, f1, 2048, fidx1, 512, part2, w2, ym, yn, pp1, sm, bid - 16);
}

__global__ __launch_bounds__(256) void fin2_kernel(const float* __restrict__ ym,
    const float* __restrict__ yn, const double2* __restrict__ pp1,
    const float* __restrict__ g2, const float* __restrict__ be2,
    float* __restrict__ f2) {
  extern __shared__ char sm[];
  fin_dev<64,128,16,512>(ym, yn, pp1, g2, be2, f2, sm, blockIdx.x);
}

__global__ __launch_bounds__(256) void conv3k4_kernel(const float* __restrict__ cq2,
    const float* __restrict__ cq1, u64* __restrict__ part4,
    const float* __restrict__ f2, const u64* __restrict__ part3,
    const float* __restrict__ w3, float* __restrict__ ym, float* __restrict__ yn,
    double2* __restrict__ pp1) {
  extern __shared__ char sm[];
  int bid = blockIdx.x;
  if (bid < 128) knn_part_dev(cq2, 128, cq1, 512, 8, part4, sm, bid);
  else           conv_dev<64,64,4,8,128>(f2, 512, f2, 512, nullptr, 512, part3, w3, ym, yn, pp1, sm, bid - 128);
}

__global__ __launch_bounds__(256) void fin3_kernel(const float* __restrict__ ym,
    const float* __restrict__ yn, const double2* __restrict__ pp1,
    const float* __restrict__ g3, const float* __restrict__ be3,
    float* __restrict__ f3) {
  extern __shared__ char sm[];
  fin_dev<64,128,16,512>(ym, yn, pp1, g3, be3, f3, sm, blockIdx.x);
}

__global__ __launch_bounds__(256) void conv4_kernel(const float* __restrict__ f3,
    const int* __restrict__ fidx2, const u64* __restrict__ part4,
    const float* __restrict__ w4, float* __restrict__ ym, float* __restrict__ yn,
    double2* __restrict__ pp1) {
  extern __shared__ char sm[];
  conv_dev<64,128,2,8,64>(f3, 512, f3, 512, fidx2, 128, part4, w4, ym, yn, pp1, sm, blockIdx.x);
}

__global__ __launch_bounds__(256) void fin4_kernel(const float* __restrict__ ym,
    const float* __restrict__ yn, const double2* __restrict__ pp1,
    const float* __restrict__ g4, const float* __restrict__ be4,
    float* __restrict__ f4) {
  extern __shared__ char sm[];
  fin_dev<128,64,8,128>(ym, yn, pp1, g4, be4, f4, sm, blockIdx.x);
}

extern "C" void kernel_launch(void* const* d_in, const int* in_sizes, int n_in,
                              void* d_out, int out_size, void* d_ws, size_t ws_size,
                              hipStream_t stream) {
  const float* x    = (const float*)d_in[0];
  const float* w_in = (const float*)d_in[3];
  const float* b_in = (const float*)d_in[4];
  const float* w1 = (const float*)d_in[5];
  const float* g1 = (const float*)d_in[6];
  const float* be1= (const float*)d_in[7];
  const float* w2 = (const float*)d_in[8];
  const float* g2 = (const float*)d_in[9];
  const float* be2= (const float*)d_in[10];
  const float* w3 = (const float*)d_in[11];
  const float* g3 = (const float*)d_in[12];
  const float* be3= (const float*)d_in[13];
  const float* w4 = (const float*)d_in[14];
  const float* g4 = (const float*)d_in[15];
  const float* be4= (const float*)d_in[16];
  float* out = (float*)d_out;
  (void)in_sizes; (void)n_in; (void)out_size; (void)ws_size;

  char* ws = (char*)d_ws;
  size_t off = 0;
  auto alloc = [&](size_t count) {        // count in 4-byte units
    void* p = ws + off;
    off += (count * 4 + 255) & ~(size_t)255;
    return p;
  };
  float* f0    = (float*)alloc(16*2048*8);
  float* f1    = (float*)alloc(16*2048*32);
  float* f2    = (float*)alloc(16*512*64);
  float* f3    = (float*)alloc(16*512*64);
  float* cq1   = (float*)alloc(16*512*3);
  float* ym    = (float*)alloc(16*2048*32);
  float* yn    = (float*)alloc(16*2048*32);
  double2* pp1 = (double2*)alloc(16*256*4*4);
  int* fidx1   = (int*)alloc(16*512);
  int* fidx2   = (int*)alloc(16*128);
  float* g_dl1 = (float*)alloc(16*2048);
  int* g_far1  = (int*)alloc(16);
  float* g_dl2 = (float*)alloc(16*512);
  int* g_far2  = (int*)alloc(16);
  u64* part1 = (u64*)alloc((size_t)2 * 16*2048*8*16);   // 33.5 MB
  u64* part2 = part1;                                   // reused post-conv1
  u64* part3 = part1 + (size_t)16*512*8*16;
  u64* part4 = part1 + (size_t)2*16*512*8*16;

  float* cq2 = out;              // (16,128,3)
  float* f4  = out + 16*128*3;   // (16,128,128)

  // dynamic-LDS sizes (union of branch needs, per kernel)
  constexpr size_t SM_F1  = 2048*16 + 2048 + 64;    // fps1 (4-wave P=8): 34880
  constexpr size_t SM_F2W = 512;                    // fps2 single-wave: s_fid only
  constexpr size_t SM_KNN = 4096;                   // KC=8 -> 256 keys staged
  constexpr size_t SM_C1  = 4096 + 8*KNN*8*4 + 8*8*4 + 8*KNN*4;       // 8960
  constexpr size_t SM_C2  = 4096 + 4*KNN*32*4 + 4*32*4 + 4*KNN*4;     // 13056
  constexpr size_t SM_C3  = 4096 + 4*KNN*64*4 + 4*64*4 + 4*KNN*4;     // 21760
  constexpr size_t SM_C4  = 4096 + 2*KNN*64*4 + 2*64*4 + 2*KNN*4;     // 12928
  constexpr size_t SM_FIN = 1056;
  auto mx2 = [](size_t a, size_t b) { return a > b ? a : b; };

  // L1: knn1(KC=8, 1024 blocks) + f0, fps1[0,280)
  fusedA_kernel<<<1168, 256, mx2(SM_F1, SM_KNN), stream>>>(x, w_in, b_in, f0, part1, fidx1, g_dl1, g_far1);
  // L1 conv + fps1[280,460)
  conv1_kernel<<<4112, 256, mx2(SM_F1, SM_C1), stream>>>(x, fidx1, g_dl1, g_far1, f0, part1, w1, ym, yn, pp1);
  // L1 fin + fps1[460,512) -> cq1
  fin1_kernel<<<528, 256, mx2(SM_F1, SM_FIN), stream>>>(x, fidx1, g_dl1, g_far1, cq1, ym, yn, pp1, g1, be1, f1);

  // L2+L3 knn (KC=8) + fps2[0,100) single-wave
  fusedB_kernel<<<528, 256, mx2(SM_F2W, SM_KNN), stream>>>(cq1, x, part2, part3, fidx2, g_dl2, g_far2);
  // L2 conv (fq rows via fidx1) + fps2[100,128) -> cq2(out)
  conv2_kernel<<<2064, 256, mx2(SM_F2W, SM_C2), stream>>>(cq1, fidx2, g_dl2, g_far2, cq2, f1, fidx1, part2, w2, ym, yn, pp1);
  fin2_kernel<<<256, 256, SM_FIN, stream>>>(ym, yn, pp1, g2, be2, f2);

  // L3 conv + L4 knn
  conv3k4_kernel<<<2176, 256, mx2(SM_KNN, SM_C3), stream>>>(cq2, cq1, part4, f2, part3, w3, ym, yn, pp1);
  fin3_kernel<<<256, 256, SM_FIN, stream>>>(ym, yn, pp1, g3, be3, f3);

  // L4 (fq rows via fidx2)
  conv4_kernel<<<1024, 256, SM_C4, stream>>>(f3, fidx2, part4, w4, ym, yn, pp1);
  fin4_kernel<<<128, 256, SM_FIN, stream>>>(ym, yn, pp1, g4, be4, f4);
}

// Round 15
// 428.275 us; speedup vs baseline: 1.1192x; 1.1192x over previous
//
#include <hip/hip_runtime.h>

#define KNN 16
static constexpr int BB = 16;
static constexpr float LEAK = 0.2f;
static constexpr float EPSV = 1e-5f;
typedef unsigned long long u64;

// ---------------- branch-free bitonic top-16 primitives -------------------
__device__ __forceinline__ void ce_asc(u64 &a, u64 &b) {
  u64 x = a, y = b; bool sw = y < x; a = sw ? y : x; b = sw ? x : y;
}
__device__ __forceinline__ void ce_desc(u64 &a, u64 &b) {
  u64 x = a, y = b; bool sw = x < y; a = sw ? y : x; b = sw ? x : y;
}
__device__ __forceinline__ void bitonic_sort16(u64 *T) {
#pragma unroll
  for (int k = 2; k <= 16; k <<= 1) {
#pragma unroll
    for (int j = k >> 1; j > 0; j >>= 1) {
#pragma unroll
      for (int i = 0; i < 16; ++i) {
        int l = i ^ j;
        if (l > i) {
          if ((i & k) == 0) ce_asc(T[i], T[l]); else ce_desc(T[i], T[l]);
        }
      }
    }
  }
}
__device__ __forceinline__ void merge_sorted16(u64 *R, const u64 *T) {
#pragma unroll
  for (int i = 0; i < 16; ++i) {
    u64 t = T[15 - i];
    R[i] = t < R[i] ? t : R[i];
  }
#pragma unroll
  for (int j = 8; j > 0; j >>= 1) {
#pragma unroll
    for (int i = 0; i < 16; ++i) {
      int l = i ^ j;
      if (l > i) ce_asc(R[i], R[l]);
    }
  }
}
template<int KC>
__device__ __forceinline__ void merge_row(const u64* __restrict__ p, u64* R) {
#pragma unroll
  for (int s = 0; s < 16; ++s) R[s] = p[s];
#pragma unroll
  for (int c = 1; c < KC; ++c) {
    u64 T[16];
#pragma unroll
    for (int s = 0; s < 16; ++s) T[s] = p[(size_t)c*KNN + s];
    merge_sorted16(R, T);
  }
}

// ---------------- device: f0 = w_in @ coor + b_in -------------------------
__device__ __forceinline__ void f0_dev(const float* __restrict__ x,
    const float* __restrict__ w_in, const float* __restrict__ b_in,
    float* __restrict__ f0, int bid) {
  int i = bid * 256 + threadIdx.x;
  float px = x[i*3+0], py = x[i*3+1], pz = x[i*3+2];
#pragma unroll
  for (int o = 0; o < 8; ++o) {
    f0[i*8+o] = w_in[o*3+0]*px + w_in[o*3+1]*py + w_in[o*3+2]*pz + b_in[o];
  }
}

// ---------------- device: kNN split-K partial top-16 ----------------------
__device__ void knn_part_dev(const float* __restrict__ qxyz, int Nq,
    const float* __restrict__ kxyz, int Nk, int KC, u64* __restrict__ part,
    char* sm, int bid) {
  float4* keys = (float4*)sm;
  int nqb = (Nq + 255) >> 8;
  int c  = bid % KC;
  int qb = (bid / KC) % nqb;
  int b  = bid / (KC * nqb);
  int nkc = Nk / KC;
  int kbase = c * nkc;
  for (int j = threadIdx.x; j < nkc; j += 256) {
    const float* kp = kxyz + (size_t)(b*Nk + kbase + j)*3;
    float kx = kp[0], ky = kp[1], kz = kp[2];
    keys[j] = make_float4(kx, ky, kz, kx*kx + ky*ky + kz*kz);
  }
  __syncthreads();
  int q = (qb << 8) + threadIdx.x;
  if (q >= Nq) return;
  const float* qp = qxyz + (size_t)(b*Nq + q)*3;
  float qx = qp[0], qy = qp[1], qz = qp[2];
  float q2 = qx*qx + qy*qy + qz*qz;
  u64 R[16];
#pragma unroll
  for (int s = 0; s < 16; ++s) R[s] = 0xFFFFFFFFFFFFFFFFull;
  for (int j0 = 0; j0 < nkc; j0 += 16) {
    u64 T[16];
#pragma unroll
    for (int u = 0; u < 16; ++u) {
      float4 kk = keys[j0 + u];
      float qk = qx*kk.x + qy*kk.y + qz*kk.z;
      float d2 = q2 + kk.w - 2.0f*qk;
      int bb = __float_as_int(d2);
      unsigned k32 = (unsigned)bb ^ (unsigned)((bb >> 31) | 0x80000000);
      T[u] = ((u64)k32 << 32) | (unsigned)(kbase + j0 + u);
    }
    bitonic_sort16(T);
    merge_sorted16(R, T);
  }
  u64* op = part + ((size_t)(b*Nq + q)*KC + c)*KNN;
#pragma unroll
  for (int s = 0; s < KNN; ++s) op[s] = R[s];
}

// ---------------- device: 4-wave FPS (fps1), f32 DPP reduce ---------------
__device__ __forceinline__ u64 fps_max64(u64 a, u64 b) { return a > b ? a : b; }
template<int CTRL>
__device__ __forceinline__ float fps_dpp_fmax(float v) {
  int nb = __builtin_amdgcn_update_dpp(0, __float_as_int(v), CTRL, 0xF, 0xF, false);
  return fmaxf(v, __int_as_float(nb));   // dl >= 0, 0-fill harmless
}
__device__ __forceinline__ float rl_f(float v, int l) {
  return __int_as_float(__builtin_amdgcn_readlane(__float_as_int(v), l));
}
template<int P, bool SAVE>
__device__ void fps_seg_dev(const float* __restrict__ xyz, int np,
    int t0, int t1, int* __restrict__ fidx,
    float* __restrict__ g_dl, int* __restrict__ g_far,
    float* __restrict__ cq, char* sm, int b) {
  constexpr int NN = P * 256;
  float4* sc  = (float4*)sm;                     // [NN]
  int* s_fid  = (int*)(sm + NN*16);              // [512]
  u64* s_key  = (u64*)(sm + NN*16 + 2048);       // [2][4]
  __builtin_amdgcn_s_setprio(1);
  int tid = threadIdx.x;
  int w = tid >> 6, lw = tid & 63;
  float px[P], py[P], pz[P], dl[P];
#pragma unroll
  for (int i = 0; i < P; ++i) {
    int p = tid * P + i;
    const float* pp = xyz + (size_t)(b*NN + p)*3;
    px[i] = pp[0]; py[i] = pp[1]; pz[i] = pp[2];
    sc[p] = make_float4(px[i], py[i], pz[i], 0.f);
  }
  int far;
  if (t0 == 0) {
#pragma unroll
    for (int i = 0; i < P; ++i) dl[i] = 1e10f;
    far = 0;
  } else {
#pragma unroll
    for (int i = 0; i < P; ++i) dl[i] = g_dl[b*NN + tid*P + i];
    far = g_far[b];
  }
  __syncthreads();
  for (int t = t0; t < t1; ++t) {
    if (tid == 0) s_fid[t] = far;
    float4 cc = sc[far];                         // uniform LDS broadcast
#pragma unroll
    for (int i = 0; i < P; ++i) {
      float dx = __fsub_rn(px[i], cc.x);
      float dy = __fsub_rn(py[i], cc.y);
      float dz = __fsub_rn(pz[i], cc.z);
      float d = __fadd_rn(__fadd_rn(__fmul_rn(dx,dx), __fmul_rn(dy,dy)), __fmul_rn(dz,dz));
      dl[i] = fminf(dl[i], d);
    }
    float m[P];
#pragma unroll
    for (int i = 0; i < P; ++i) m[i] = dl[i];
#pragma unroll
    for (int st = P/2; st > 0; st >>= 1) {
#pragma unroll
      for (int i = 0; i < P; ++i) if (i < st) m[i] = fmaxf(m[i], m[i + st]);
    }
    float lmax = m[0];
    unsigned msk = 0u;
#pragma unroll
    for (int i = 0; i < P; ++i) msk |= (dl[i] == lmax) ? (1u << i) : 0u;
    int lidx = tid * P + __builtin_ctz(msk);     // lowest p in this thread
    float v = lmax;
    v = fps_dpp_fmax<0x111>(v);  // row_shr:1
    v = fps_dpp_fmax<0x112>(v);  // row_shr:2
    v = fps_dpp_fmax<0x114>(v);  // row_shr:4
    v = fps_dpp_fmax<0x118>(v);  // row_shr:8
    v = fps_dpp_fmax<0x142>(v);  // row_bcast:15
    v = fps_dpp_fmax<0x143>(v);  // row_bcast:31
    float wmax = rl_f(v, 63);
    u64 bal = __ballot(lmax == wmax);
    int l0 = __ffsll((unsigned long long)bal) - 1;
    int wp = __builtin_amdgcn_readlane(lidx, l0);
    int buf = t & 1;
    if (lw == 0)
      s_key[buf*4 + w] = ((u64)__float_as_uint(wmax) << 32) | (unsigned)(~wp);
    __syncthreads();
    u64 best = s_key[buf*4 + 0];
    best = fps_max64(best, s_key[buf*4 + 1]);
    best = fps_max64(best, s_key[buf*4 + 2]);
    best = fps_max64(best, s_key[buf*4 + 3]);
    far = (int)(~(unsigned)(best & 0xFFFFFFFFull));
  }
  // batched fidx writes (s_fid visible: last iteration ended in a barrier)
  for (int t = t0 + tid; t < t1; t += 256) fidx[b*np + t] = s_fid[t];
  if constexpr (SAVE) {
#pragma unroll
    for (int i = 0; i < P; ++i) g_dl[b*NN + tid*P + i] = dl[i];
    if (tid == 0) g_far[b] = far;
  } else {
    for (int j = tid; j < np; j += 256) {
      int p = (j >= t0) ? s_fid[j] : fidx[b*np + j];
      float4 c = sc[p];
      float* cp = cq + (size_t)(b*np + j)*3;
      cp[0] = c.x; cp[1] = c.y; cp[2] = c.z;
    }
  }
  __builtin_amdgcn_s_setprio(0);
}

// ---------------- device: SINGLE-WAVE FPS (fps2), full run, no barriers ---
template<int P>
__device__ void fps2_wave_dev(const float* __restrict__ xyz, int np,
    int* __restrict__ fidx, float* __restrict__ cq, char* sm, int b) {
  constexpr int NN = P * 64;
  int* s_fid = (int*)sm;                         // [np]
  __builtin_amdgcn_s_setprio(1);
  int l = threadIdx.x;                           // 0..63
  float px[P], py[P], pz[P], dl[P];
#pragma unroll
  for (int i = 0; i < P; ++i) {
    int p = l * P + i;
    const float* pp = xyz + (size_t)(b*NN + p)*3;
    px[i] = pp[0]; py[i] = pp[1]; pz[i] = pp[2];
    dl[i] = 1e10f;
  }
  int far = 0;
  const float* fp = xyz + (size_t)(b*NN)*3;
  float ccx = fp[0], ccy = fp[1], ccz = fp[2];
  for (int t = 0; t < np; ++t) {
    if (l == 0) s_fid[t] = far;
#pragma unroll
    for (int i = 0; i < P; ++i) {
      float dx = __fsub_rn(px[i], ccx);
      float dy = __fsub_rn(py[i], ccy);
      float dz = __fsub_rn(pz[i], ccz);
      float d = __fadd_rn(__fadd_rn(__fmul_rn(dx,dx), __fmul_rn(dy,dy)), __fmul_rn(dz,dz));
      dl[i] = fminf(dl[i], d);
    }
    float m[P];
#pragma unroll
    for (int i = 0; i < P; ++i) m[i] = dl[i];
#pragma unroll
    for (int st = P/2; st > 0; st >>= 1) {
#pragma unroll
      for (int i = 0; i < P; ++i) if (i < st) m[i] = fmaxf(m[i], m[i + st]);
    }
    float lmax = m[0];
    unsigned msk = 0u;
#pragma unroll
    for (int i = 0; i < P; ++i) msk |= (dl[i] == lmax) ? (1u << i) : 0u;
    int ib = __builtin_ctz(msk);
    int lidx = l * P + ib;
    float cxl = px[P-1], cyl = py[P-1], czl = pz[P-1];
#pragma unroll
    for (int i = P-1; i >= 0; --i) {
      bool tk = (msk >> i) & 1u;
      cxl = tk ? px[i] : cxl;
      cyl = tk ? py[i] : cyl;
      czl = tk ? pz[i] : czl;
    }
    float v = lmax;
    v = fps_dpp_fmax<0x111>(v);
    v = fps_dpp_fmax<0x112>(v);
    v = fps_dpp_fmax<0x114>(v);
    v = fps_dpp_fmax<0x118>(v);
    v = fps_dpp_fmax<0x142>(v);
    v = fps_dpp_fmax<0x143>(v);
    float wmax = rl_f(v, 63);
    u64 bal = __ballot(lmax == wmax);
    int l0 = __ffsll((unsigned long long)bal) - 1;   // lowest lane = lowest p
    far = __builtin_amdgcn_readlane(lidx, l0);
    ccx = rl_f(cxl, l0); ccy = rl_f(cyl, l0); ccz = rl_f(czl, l0);
  }
  for (int t = l; t < np; t += 64) {
    int p = s_fid[t];
    fidx[b*np + t] = p;
    const float* sp = xyz + (size_t)(b*NN + p)*3;
    float* cp = cq + (size_t)(b*np + t)*3;
    cp[0] = sp[0]; cp[1] = sp[1]; cp[2] = sp[2];
  }
  __builtin_amdgcn_s_setprio(0);
}

// ---------------- device: conv + fused GN stats + minmax over k ----------
// qmap remaps BOTH the fq row and the part row: query j's source row is
// qmap[b*Nq+j] in [0,Nsrc) — folds the FPS gather AND the kNN-row identity
// (idx_layer(j) == idx_prev(qmap[j])) into the conv load.
template<int C, int O, int QB, int KC, int NB>
__device__ void conv_dev(const float* __restrict__ fsrc, int Nsrc,
    const int* __restrict__ qmap, int Nq, const u64* __restrict__ part,
    const float* __restrict__ w, float* __restrict__ ym, float* __restrict__ yn,
    double2* __restrict__ pp1, char* sm, int bid) {
  constexpr int Og = O / 4;
  constexpr int C4 = C / 4;
  double* rs  = (double*)sm;                    // [256]
  double* rs2 = rs + 256;                       // [256]
  float* ft   = (float*)(sm + 4096);            // [QB][KNN][C]
  float* fqs  = ft + QB*KNN*C;                  // [QB][C]
  int* s_idx  = (int*)(fqs + QB*C);             // [QB][KNN]
  int tid = threadIdx.x;
  int chunk = bid % NB;
  int b = bid / NB;
  int q0 = chunk * QB;
  if (tid < QB) {
    int q = q0 + tid;
    int sq = qmap ? qmap[b*Nq + q] : q;
    const u64* p = part + ((size_t)b*Nsrc + sq)*KC*KNN;
    u64 R[16];
    merge_row<KC>(p, R);
#pragma unroll
    for (int s = 0; s < 16; ++s) s_idx[tid*KNN + s] = (int)(unsigned)(R[s] & 0xFFFFFFFFu);
  } else if (tid >= 64 && tid < 64 + QB*C4) {
    int t = tid - 64;
    int ql = t / C4, c4 = t % C4;
    int q = q0 + ql;
    int sq = qmap ? qmap[b*Nq + q] : q;
    ((float4*)&fqs[ql*C])[c4] = ((const float4*)(fsrc + ((size_t)b*Nsrc + sq)*C))[c4];
  }
  __syncthreads();
  for (int v = tid; v < QB*KNN*C4; v += 256) {
    int row = v / C4, c4 = v % C4;
    int ql = row / KNN, k = row % KNN;
    int src = s_idx[ql*KNN + k];
    ((float4*)&ft[(ql*KNN + k)*C])[c4] = ((const float4*)(fsrc + (size_t)(b*Nsrc + src)*C))[c4];
  }
  __syncthreads();
  int ql = tid / O, o = tid % O;
  float4 wr4[C4];
  float bs = 0.f;
  const float4* wp4 = (const float4*)(w + (size_t)o*2*C);
#pragma unroll
  for (int c4 = 0; c4 < C4; ++c4) {
    float4 lo = wp4[c4], hi = wp4[C4 + c4];
    float4 fv = ((const float4*)&fqs[ql*C])[c4];
    bs += (hi.x - lo.x) * fv.x;
    bs += (hi.y - lo.y) * fv.y;
    bs += (hi.z - lo.z) * fv.z;
    bs += (hi.w - lo.w) * fv.w;
    wr4[c4] = lo;
  }
  float mx = -3.4e38f, mn = 3.4e38f;
  double s = 0.0, s2 = 0.0;
  for (int k = 0; k < KNN; ++k) {
    float acc = bs;
    const float4* fv = (const float4*)&ft[(ql*KNN + k)*C];
#pragma unroll
    for (int c4 = 0; c4 < C4; ++c4) {
      float4 v = fv[c4];
      acc += wr4[c4].x*v.x; acc += wr4[c4].y*v.y;
      acc += wr4[c4].z*v.z; acc += wr4[c4].w*v.w;
    }
    mx = fmaxf(mx, acc);
    mn = fminf(mn, acc);
    s += acc;
    s2 += (double)acc * (double)acc;
  }
  size_t oidx = (size_t)(b*Nq + q0 + ql)*O + o;
  ym[oidx] = mx;
  yn[oidx] = mn;
  rs[tid] = s; rs2[tid] = s2;
  __syncthreads();
#pragma unroll
  for (int st = QB/2; st > 0; st >>= 1) {
    if (ql < st) { rs[tid] += rs[tid + st*O]; rs2[tid] += rs2[tid + st*O]; }
    __syncthreads();
  }
#pragma unroll
  for (int st = Og/2; st > 0; st >>= 1) {
    if (tid < O && (o % Og) < st) { rs[tid] += rs[tid + st]; rs2[tid] += rs2[tid + st]; }
    __syncthreads();
  }
  if (tid < O && (o % Og) == 0) {
    int g = o / Og;
    pp1[((size_t)b*NB + chunk)*4 + g] = make_double2(rs[tid], rs2[tid]);
  }
}

// ---------------- device: finalize (GN + lrelu from minmax) ---------------
template<int O, int NB, int FCH, int NQ>
__device__ void fin_dev(const float* __restrict__ ym, const float* __restrict__ yn,
    const double2* __restrict__ pp1, const float* __restrict__ gamma,
    const float* __restrict__ beta, float* __restrict__ fout, char* sm, int bid) {
  constexpr int Og = O / 4;
  double* red  = (double*)sm;                   // [64]
  double* red2 = red + 64;                      // [64]
  float* s_mu  = (float*)(red2 + 64);           // [4]
  float* s_rsv = s_mu + 4;                      // [4]
  int tid = threadIdx.x;
  int b = bid / FCH;
  int f = bid % FCH;
  if (tid < 64) {
    int g = tid >> 4, j = tid & 15;
    double s = 0.0, s2 = 0.0;
    for (int c = j; c < NB; c += 16) {
      double2 v = pp1[((size_t)b*NB + c)*4 + g];
      s += v.x; s2 += v.y;
    }
    red[tid] = s; red2[tid] = s2;
  }
  __syncthreads();
#pragma unroll
  for (int st = 8; st > 0; st >>= 1) {
    if (tid < 64 && (tid & 15) < st) { red[tid] += red[tid+st]; red2[tid] += red2[tid+st]; }
    __syncthreads();
  }
  if (tid < 4) {
    double cnt = (double)Og * (double)NQ * (double)KNN;
    double mu = red[tid*16] / cnt;
    double var = red2[tid*16] / cnt - mu*mu;
    s_mu[tid] = (float)mu;
    s_rsv[tid] = 1.0f / sqrtf((float)var + EPSV);
  }
  __syncthreads();
  constexpr int PER = NQ * O / FCH;
  int e0 = f * PER;
  for (int e = e0 + tid; e < e0 + PER; e += 256) {
    int q = e / O, o = e % O;
    int g = o / Og;
    size_t idx = (size_t)(b*NQ + q)*O + o;
    float ga = gamma[o], be = beta[o];
    float ysel = (ga >= 0.f) ? ym[idx] : yn[idx];
    float xn = (ysel - s_mu[g]) * s_rsv[g];
    float yv = xn*ga + be;
    yv = yv > 0.f ? yv : LEAK*yv;
    fout[idx] = yv;
  }
}

// ---------------- dispatch wrappers (dynamic shared) ----------------------
__global__ __launch_bounds__(256) void fusedA_kernel(const float* __restrict__ x,
    const float* __restrict__ w_in, const float* __restrict__ b_in,
    float* __restrict__ f0, u64* __restrict__ part, int* __restrict__ fidx1,
    float* __restrict__ g_dl, int* __restrict__ g_far) {
  extern __shared__ char sm[];
  int bid = blockIdx.x;
  if (bid < 16)        fps_seg_dev<8,true>(x, 512, 0, 280, fidx1, g_dl, g_far, nullptr, sm, bid);
  else if (bid < 1040) knn_part_dev(x, 2048, x, 2048, 8, part, sm, bid - 16);
  else                 f0_dev(x, w_in, b_in, f0, bid - 1040);
}

__global__ __launch_bounds__(256) void conv1_kernel(const float* __restrict__ x,
    int* __restrict__ fidx1, float* __restrict__ g_dl, int* __restrict__ g_far,
    const float* __restrict__ f0, const u64* __restrict__ part,
    const float* __restrict__ w1, float* __restrict__ ym, float* __restrict__ yn,
    double2* __restrict__ pp1) {
  extern __shared__ char sm[];
  int bid = blockIdx.x;
  if (bid < 16) fps_seg_dev<8,true>(x, 512, 280, 460, fidx1, g_dl, g_far, nullptr, sm, bid);
  else          conv_dev<8,32,8,8,256>(f0, 2048, nullptr, 2048, part, w1, ym, yn, pp1, sm, bid - 16);
}

__global__ __launch_bounds__(256) void fin1_kernel(const float* __restrict__ x,
    int* __restrict__ fidx1, float* __restrict__ g_dl, int* __restrict__ g_far,
    float* __restrict__ cq1,
    const float* __restrict__ ym, const float* __restrict__ yn,
    const double2* __restrict__ pp1, const float* __restrict__ g1,
    const float* __restrict__ be1, float* __restrict__ f1) {
  extern __shared__ char sm[];
  int bid = blockIdx.x;
  if (bid < 16) fps_seg_dev<8,false>(x, 512, 460, 512, fidx1, g_dl, g_far, cq1, sm, bid);
  else          fin_dev<32,256,32,2048>(ym, yn, pp1, g1, be1, f1, sm, bid - 16);
}

// conv2 dispatch also carries fps2 (full 128 steps) and knn3.
__global__ __launch_bounds__(256) void conv2_kernel(const float* __restrict__ cq1,
    int* __restrict__ fidx2, float* __restrict__ cq2, u64* __restrict__ part3,
    const float* __restrict__ f1, const int* __restrict__ fidx1,
    const u64* __restrict__ part1, const float* __restrict__ w2,
    float* __restrict__ ym, float* __restrict__ yn, double2* __restrict__ pp1) {
  extern __shared__ char sm[];
  int bid = blockIdx.x;
  if (bid < 16) {
    if (threadIdx.x < 64)
      fps2_wave_dev<8>(cq1, 128, fidx2, cq2, sm, bid);
  } else if (bid < 272) {
    knn_part_dev(cq1, 512, cq1, 512, 8, part3, sm, bid - 16);
  } else {
    conv_dev<32,64,4,8,128>(f1, 2048, fidx1, 512, part1, w2, ym, yn, pp1, sm, bid - 272);
  }
}

__global__ __launch_bounds__(256) void fin2_kernel(const float* __restrict__ ym,
    const float* __restrict__ yn, const double2* __restrict__ pp1,
    const float* __restrict__ g2, const float* __restrict__ be2,
    float* __restrict__ f2) {
  extern __shared__ char sm[];
  fin_dev<64,128,16,512>(ym, yn, pp1, g2, be2, f2, sm, blockIdx.x);
}

__global__ __launch_bounds__(256) void conv3_kernel(const float* __restrict__ f2,
    const u64* __restrict__ part3, const float* __restrict__ w3,
    float* __restrict__ ym, float* __restrict__ yn, double2* __restrict__ pp1) {
  extern __shared__ char sm[];
  conv_dev<64,64,4,8,128>(f2, 512, nullptr, 512, part3, w3, ym, yn, pp1, sm, blockIdx.x);
}

__global__ __launch_bounds__(256) void fin3_kernel(const float* __restrict__ ym,
    const float* __restrict__ yn, const double2* __restrict__ pp1,
    const float* __restrict__ g3, const float* __restrict__ be3,
    float* __restrict__ f3) {
  extern __shared__ char sm[];
  fin_dev<64,128,16,512>(ym, yn, pp1, g3, be3, f3, sm, blockIdx.x);
}

__global__ __launch_bounds__(256) void conv4_kernel(const float* __restrict__ f3,
    const int* __restrict__ fidx2, const u64* __restrict__ part3,
    const float* __restrict__ w4, float* __restrict__ ym, float* __restrict__ yn,
    double2* __restrict__ pp1) {
  extern __shared__ char sm[];
  conv_dev<64,128,2,8,64>(f3, 512, fidx2, 128, part3, w4, ym, yn, pp1, sm, blockIdx.x);
}

__global__ __launch_bounds__(256) void fin4_kernel(const float* __restrict__ ym,
    const float* __restrict__ yn, const double2* __restrict__ pp1,
    const float* __restrict__ g4, const float* __restrict__ be4,
    float* __restrict__ f4) {
  extern __shared__ char sm[];
  fin_dev<128,64,8,128>(ym, yn, pp1, g4, be4, f4, sm, blockIdx.x);
}

extern "C" void kernel_launch(void* const* d_in, const int* in_sizes, int n_in,
                              void* d_out, int out_size, void* d_ws, size_t ws_size,
                              hipStream_t stream) {
  const float* x    = (const float*)d_in[0];
  const float* w_in = (const float*)d_in[3];
  const float* b_in = (const float*)d_in[4];
  const float* w1 = (const float*)d_in[5];
  const float* g1 = (const float*)d_in[6];
  const float* be1= (const float*)d_in[7];
  const float* w2 = (const float*)d_in[8];
  const float* g2 = (const float*)d_in[9];
  const float* be2= (const float*)d_in[10];
  const float* w3 = (const float*)d_in[11];
  const float* g3 = (const float*)d_in[12];
  const float* be3= (const float*)d_in[13];
  const float* w4 = (const float*)d_in[14];
  const float* g4 = (const float*)d_in[15];
  const float* be4= (const float*)d_in[16];
  float* out = (float*)d_out;
  (void)in_sizes; (void)n_in; (void)out_size; (void)ws_size;

  char* ws = (char*)d_ws;
  size_t off = 0;
  auto alloc = [&](size_t count) {        // count in 4-byte units
    void* p = ws + off;
    off += (count * 4 + 255) & ~(size_t)255;
    return p;
  };
  float* f0    = (float*)alloc(16*2048*8);
  float* f1    = (float*)alloc(16*2048*32);
  float* f2    = (float*)alloc(16*512*64);
  float* f3    = (float*)alloc(16*512*64);
  float* cq1   = (float*)alloc(16*512*3);
  float* ym    = (float*)alloc(16*2048*32);
  float* yn    = (float*)alloc(16*2048*32);
  double2* pp1 = (double2*)alloc(16*256*4*4);
  int* fidx1   = (int*)alloc(16*512);
  int* fidx2   = (int*)alloc(16*128);
  float* g_dl1 = (float*)alloc(16*2048);
  int* g_far1  = (int*)alloc(16);
  u64* part1 = (u64*)alloc((size_t)2 * 16*2048*8*16);   // 33.5 MB (knn1, live thru conv2)
  u64* part3 = (u64*)alloc((size_t)2 * 16*512*8*16);    // 8.4 MB (knn3, live thru conv4)

  float* cq2 = out;              // (16,128,3)
  float* f4  = out + 16*128*3;   // (16,128,128)

  // dynamic-LDS sizes (union of branch needs, per kernel)
  constexpr size_t SM_F1  = 2048*16 + 2048 + 64;    // fps1 (4-wave P=8): 34880
  constexpr size_t SM_F2W = 512;                    // fps2 single-wave: s_fid only
  constexpr size_t SM_KNN = 4096;                   // KC=8 -> 256 keys staged
  constexpr size_t SM_C1  = 4096 + 8*KNN*8*4 + 8*8*4 + 8*KNN*4;       // 8960
  constexpr size_t SM_C2  = 4096 + 4*KNN*32*4 + 4*32*4 + 4*KNN*4;     // 13056
  constexpr size_t SM_C3  = 4096 + 4*KNN*64*4 + 4*64*4 + 4*KNN*4;     // 21760
  constexpr size_t SM_C4  = 4096 + 2*KNN*64*4 + 2*64*4 + 2*KNN*4;     // 12928
  constexpr size_t SM_FIN = 1056;
  auto mx2 = [](size_t a, size_t b) { return a > b ? a : b; };
  auto mx3 = [&](size_t a, size_t b, size_t c) { return mx2(a, mx2(b, c)); };

  // L1: knn1(KC=8, 1024 blocks) + f0, fps1[0,280)
  fusedA_kernel<<<1168, 256, mx2(SM_F1, SM_KNN), stream>>>(x, w_in, b_in, f0, part1, fidx1, g_dl1, g_far1);
  // L1 conv + fps1[280,460)
  conv1_kernel<<<4112, 256, mx2(SM_F1, SM_C1), stream>>>(x, fidx1, g_dl1, g_far1, f0, part1, w1, ym, yn, pp1);
  // L1 fin + fps1[460,512) -> cq1
  fin1_kernel<<<528, 256, mx2(SM_F1, SM_FIN), stream>>>(x, fidx1, g_dl1, g_far1, cq1, ym, yn, pp1, g1, be1, f1);

  // L2 conv (kNN rows = part1 at fidx1) + fps2 full (-> fidx2, cq2) + knn3
  conv2_kernel<<<2320, 256, mx3(SM_F2W, SM_KNN, SM_C2), stream>>>(cq1, fidx2, cq2, part3,
      f1, fidx1, part1, w2, ym, yn, pp1);
  fin2_kernel<<<256, 256, SM_FIN, stream>>>(ym, yn, pp1, g2, be2, f2);

  // L3 conv (part3 direct)
  conv3_kernel<<<2048, 256, SM_C3, stream>>>(f2, part3, w3, ym, yn, pp1);
  fin3_kernel<<<256, 256, SM_FIN, stream>>>(ym, yn, pp1, g3, be3, f3);

  // L4 conv (kNN rows = part3 at fidx2)
  conv4_kernel<<<1024, 256, SM_C4, stream>>>(f3, fidx2, part3, w4, ym, yn, pp1);
  fin4_kernel<<<128, 256, SM_FIN, stream>>>(ym, yn, pp1, g4, be4, f4);
}

// Round 16
// 384.737 us; speedup vs baseline: 1.2458x; 1.1132x over previous
//
#include <hip/hip_runtime.h>

#define KNN 16
static constexpr int BB = 16;
static constexpr float LEAK = 0.2f;
static constexpr float EPSV = 1e-5f;
typedef unsigned long long u64;

// ---------------- branch-free bitonic top-16 primitives -------------------
__device__ __forceinline__ void ce_asc(u64 &a, u64 &b) {
  u64 x = a, y = b; bool sw = y < x; a = sw ? y : x; b = sw ? x : y;
}
__device__ __forceinline__ void ce_desc(u64 &a, u64 &b) {
  u64 x = a, y = b; bool sw = x < y; a = sw ? y : x; b = sw ? x : y;
}
__device__ __forceinline__ void bitonic_sort16(u64 *T) {
#pragma unroll
  for (int k = 2; k <= 16; k <<= 1) {
#pragma unroll
    for (int j = k >> 1; j > 0; j >>= 1) {
#pragma unroll
      for (int i = 0; i < 16; ++i) {
        int l = i ^ j;
        if (l > i) {
          if ((i & k) == 0) ce_asc(T[i], T[l]); else ce_desc(T[i], T[l]);
        }
      }
    }
  }
}
__device__ __forceinline__ void merge_sorted16(u64 *R, const u64 *T) {
#pragma unroll
  for (int i = 0; i < 16; ++i) {
    u64 t = T[15 - i];
    R[i] = t < R[i] ? t : R[i];
  }
#pragma unroll
  for (int j = 8; j > 0; j >>= 1) {
#pragma unroll
    for (int i = 0; i < 16; ++i) {
      int l = i ^ j;
      if (l > i) ce_asc(R[i], R[l]);
    }
  }
}
template<int KC>
__device__ __forceinline__ void merge_row(const u64* __restrict__ p, u64* R) {
#pragma unroll
  for (int s = 0; s < 16; ++s) R[s] = p[s];
#pragma unroll
  for (int c = 1; c < KC; ++c) {
    u64 T[16];
#pragma unroll
    for (int s = 0; s < 16; ++s) T[s] = p[(size_t)c*KNN + s];
    merge_sorted16(R, T);
  }
}

// ---------------- device: compact KC=8 partials -> final sorted row -------
// One ROW PER LANE: full exec mask, 64 rows per wave per pass of the network.
__device__ __forceinline__ void compact_dev(const u64* __restrict__ part,
    u64* __restrict__ outIdx, int rows, int bid) {
  int r = bid * 256 + threadIdx.x;
  if (r >= rows) return;
  u64 R[16];
  merge_row<8>(part + (size_t)r * 8 * KNN, R);
  u64* op = outIdx + (size_t)r * KNN;
#pragma unroll
  for (int s = 0; s < 16; ++s) op[s] = R[s];
}

// ---------------- device: f0 = w_in @ coor + b_in -------------------------
__device__ __forceinline__ void f0_dev(const float* __restrict__ x,
    const float* __restrict__ w_in, const float* __restrict__ b_in,
    float* __restrict__ f0, int bid) {
  int i = bid * 256 + threadIdx.x;
  float px = x[i*3+0], py = x[i*3+1], pz = x[i*3+2];
#pragma unroll
  for (int o = 0; o < 8; ++o) {
    f0[i*8+o] = w_in[o*3+0]*px + w_in[o*3+1]*py + w_in[o*3+2]*pz + b_in[o];
  }
}

// ---------------- device: kNN split-K partial top-16 ----------------------
__device__ void knn_part_dev(const float* __restrict__ qxyz, int Nq,
    const float* __restrict__ kxyz, int Nk, int KC, u64* __restrict__ part,
    char* sm, int bid) {
  float4* keys = (float4*)sm;
  int nqb = (Nq + 255) >> 8;
  int c  = bid % KC;
  int qb = (bid / KC) % nqb;
  int b  = bid / (KC * nqb);
  int nkc = Nk / KC;
  int kbase = c * nkc;
  for (int j = threadIdx.x; j < nkc; j += 256) {
    const float* kp = kxyz + (size_t)(b*Nk + kbase + j)*3;
    float kx = kp[0], ky = kp[1], kz = kp[2];
    keys[j] = make_float4(kx, ky, kz, kx*kx + ky*ky + kz*kz);
  }
  __syncthreads();
  int q = (qb << 8) + threadIdx.x;
  if (q >= Nq) return;
  const float* qp = qxyz + (size_t)(b*Nq + q)*3;
  float qx = qp[0], qy = qp[1], qz = qp[2];
  float q2 = qx*qx + qy*qy + qz*qz;
  u64 R[16];
#pragma unroll
  for (int s = 0; s < 16; ++s) R[s] = 0xFFFFFFFFFFFFFFFFull;
  for (int j0 = 0; j0 < nkc; j0 += 16) {
    u64 T[16];
#pragma unroll
    for (int u = 0; u < 16; ++u) {
      float4 kk = keys[j0 + u];
      float qk = qx*kk.x + qy*kk.y + qz*kk.z;
      float d2 = q2 + kk.w - 2.0f*qk;
      int bb = __float_as_int(d2);
      unsigned k32 = (unsigned)bb ^ (unsigned)((bb >> 31) | 0x80000000);
      T[u] = ((u64)k32 << 32) | (unsigned)(kbase + j0 + u);
    }
    bitonic_sort16(T);
    merge_sorted16(R, T);
  }
  u64* op = part + ((size_t)(b*Nq + q)*KC + c)*KNN;
#pragma unroll
  for (int s = 0; s < KNN; ++s) op[s] = R[s];
}

// ---------------- device: 4-wave FPS (fps1), f32 DPP reduce ---------------
__device__ __forceinline__ u64 fps_max64(u64 a, u64 b) { return a > b ? a : b; }
template<int CTRL>
__device__ __forceinline__ float fps_dpp_fmax(float v) {
  int nb = __builtin_amdgcn_update_dpp(0, __float_as_int(v), CTRL, 0xF, 0xF, false);
  return fmaxf(v, __int_as_float(nb));   // dl >= 0, 0-fill harmless
}
__device__ __forceinline__ float rl_f(float v, int l) {
  return __int_as_float(__builtin_amdgcn_readlane(__float_as_int(v), l));
}
template<int P, bool SAVE>
__device__ void fps_seg_dev(const float* __restrict__ xyz, int np,
    int t0, int t1, int* __restrict__ fidx,
    float* __restrict__ g_dl, int* __restrict__ g_far,
    float* __restrict__ cq, char* sm, int b) {
  constexpr int NN = P * 256;
  float4* sc  = (float4*)sm;                     // [NN]
  int* s_fid  = (int*)(sm + NN*16);              // [512]
  u64* s_key  = (u64*)(sm + NN*16 + 2048);       // [2][4]
  __builtin_amdgcn_s_setprio(1);
  int tid = threadIdx.x;
  int w = tid >> 6, lw = tid & 63;
  float px[P], py[P], pz[P], dl[P];
#pragma unroll
  for (int i = 0; i < P; ++i) {
    int p = tid * P + i;
    const float* pp = xyz + (size_t)(b*NN + p)*3;
    px[i] = pp[0]; py[i] = pp[1]; pz[i] = pp[2];
    sc[p] = make_float4(px[i], py[i], pz[i], 0.f);
  }
  int far;
  if (t0 == 0) {
#pragma unroll
    for (int i = 0; i < P; ++i) dl[i] = 1e10f;
    far = 0;
  } else {
#pragma unroll
    for (int i = 0; i < P; ++i) dl[i] = g_dl[b*NN + tid*P + i];
    far = g_far[b];
  }
  __syncthreads();
  for (int t = t0; t < t1; ++t) {
    if (tid == 0) s_fid[t] = far;
    float4 cc = sc[far];                         // uniform LDS broadcast
#pragma unroll
    for (int i = 0; i < P; ++i) {
      float dx = __fsub_rn(px[i], cc.x);
      float dy = __fsub_rn(py[i], cc.y);
      float dz = __fsub_rn(pz[i], cc.z);
      float d = __fadd_rn(__fadd_rn(__fmul_rn(dx,dx), __fmul_rn(dy,dy)), __fmul_rn(dz,dz));
      dl[i] = fminf(dl[i], d);
    }
    float m[P];
#pragma unroll
    for (int i = 0; i < P; ++i) m[i] = dl[i];
#pragma unroll
    for (int st = P/2; st > 0; st >>= 1) {
#pragma unroll
      for (int i = 0; i < P; ++i) if (i < st) m[i] = fmaxf(m[i], m[i + st]);
    }
    float lmax = m[0];
    unsigned msk = 0u;
#pragma unroll
    for (int i = 0; i < P; ++i) msk |= (dl[i] == lmax) ? (1u << i) : 0u;
    int lidx = tid * P + __builtin_ctz(msk);     // lowest p in this thread
    float v = lmax;
    v = fps_dpp_fmax<0x111>(v);  // row_shr:1
    v = fps_dpp_fmax<0x112>(v);  // row_shr:2
    v = fps_dpp_fmax<0x114>(v);  // row_shr:4
    v = fps_dpp_fmax<0x118>(v);  // row_shr:8
    v = fps_dpp_fmax<0x142>(v);  // row_bcast:15
    v = fps_dpp_fmax<0x143>(v);  // row_bcast:31
    float wmax = rl_f(v, 63);
    u64 bal = __ballot(lmax == wmax);
    int l0 = __ffsll((unsigned long long)bal) - 1;
    int wp = __builtin_amdgcn_readlane(lidx, l0);
    int buf = t & 1;
    if (lw == 0)
      s_key[buf*4 + w] = ((u64)__float_as_uint(wmax) << 32) | (unsigned)(~wp);
    __syncthreads();
    u64 best = s_key[buf*4 + 0];
    best = fps_max64(best, s_key[buf*4 + 1]);
    best = fps_max64(best, s_key[buf*4 + 2]);
    best = fps_max64(best, s_key[buf*4 + 3]);
    far = (int)(~(unsigned)(best & 0xFFFFFFFFull));
  }
  // batched fidx writes (s_fid visible: last iteration ended in a barrier)
  for (int t = t0 + tid; t < t1; t += 256) fidx[b*np + t] = s_fid[t];
  if constexpr (SAVE) {
#pragma unroll
    for (int i = 0; i < P; ++i) g_dl[b*NN + tid*P + i] = dl[i];
    if (tid == 0) g_far[b] = far;
  } else {
    for (int j = tid; j < np; j += 256) {
      int p = (j >= t0) ? s_fid[j] : fidx[b*np + j];
      float4 c = sc[p];
      float* cp = cq + (size_t)(b*np + j)*3;
      cp[0] = c.x; cp[1] = c.y; cp[2] = c.z;
    }
  }
  __builtin_amdgcn_s_setprio(0);
}

// ---------------- device: SINGLE-WAVE FPS (fps2), full run, no barriers ---
template<int P>
__device__ void fps2_wave_dev(const float* __restrict__ xyz, int np,
    int* __restrict__ fidx, float* __restrict__ cq, char* sm, int b) {
  constexpr int NN = P * 64;
  int* s_fid = (int*)sm;                         // [np]
  __builtin_amdgcn_s_setprio(1);
  int l = threadIdx.x;                           // 0..63
  float px[P], py[P], pz[P], dl[P];
#pragma unroll
  for (int i = 0; i < P; ++i) {
    int p = l * P + i;
    const float* pp = xyz + (size_t)(b*NN + p)*3;
    px[i] = pp[0]; py[i] = pp[1]; pz[i] = pp[2];
    dl[i] = 1e10f;
  }
  int far = 0;
  const float* fp = xyz + (size_t)(b*NN)*3;
  float ccx = fp[0], ccy = fp[1], ccz = fp[2];
  for (int t = 0; t < np; ++t) {
    if (l == 0) s_fid[t] = far;
#pragma unroll
    for (int i = 0; i < P; ++i) {
      float dx = __fsub_rn(px[i], ccx);
      float dy = __fsub_rn(py[i], ccy);
      float dz = __fsub_rn(pz[i], ccz);
      float d = __fadd_rn(__fadd_rn(__fmul_rn(dx,dx), __fmul_rn(dy,dy)), __fmul_rn(dz,dz));
      dl[i] = fminf(dl[i], d);
    }
    float m[P];
#pragma unroll
    for (int i = 0; i < P; ++i) m[i] = dl[i];
#pragma unroll
    for (int st = P/2; st > 0; st >>= 1) {
#pragma unroll
      for (int i = 0; i < P; ++i) if (i < st) m[i] = fmaxf(m[i], m[i + st]);
    }
    float lmax = m[0];
    unsigned msk = 0u;
#pragma unroll
    for (int i = 0; i < P; ++i) msk |= (dl[i] == lmax) ? (1u << i) : 0u;
    int ib = __builtin_ctz(msk);
    int lidx = l * P + ib;
    float cxl = px[P-1], cyl = py[P-1], czl = pz[P-1];
#pragma unroll
    for (int i = P-1; i >= 0; --i) {
      bool tk = (msk >> i) & 1u;
      cxl = tk ? px[i] : cxl;
      cyl = tk ? py[i] : cyl;
      czl = tk ? pz[i] : czl;
    }
    float v = lmax;
    v = fps_dpp_fmax<0x111>(v);
    v = fps_dpp_fmax<0x112>(v);
    v = fps_dpp_fmax<0x114>(v);
    v = fps_dpp_fmax<0x118>(v);
    v = fps_dpp_fmax<0x142>(v);
    v = fps_dpp_fmax<0x143>(v);
    float wmax = rl_f(v, 63);
    u64 bal = __ballot(lmax == wmax);
    int l0 = __ffsll((unsigned long long)bal) - 1;   // lowest lane = lowest p
    far = __builtin_amdgcn_readlane(lidx, l0);
    ccx = rl_f(cxl, l0); ccy = rl_f(cyl, l0); ccz = rl_f(czl, l0);
  }
  for (int t = l; t < np; t += 64) {
    int p = s_fid[t];
    fidx[b*np + t] = p;
    const float* sp = xyz + (size_t)(b*NN + p)*3;
    float* cp = cq + (size_t)(b*np + t)*3;
    cp[0] = sp[0]; cp[1] = sp[1]; cp[2] = sp[2];
  }
  __builtin_amdgcn_s_setprio(0);
}

// ---------------- device: conv + fused GN stats + minmax over k ----------
// qmap remaps BOTH the fq row and the part/idx row. KC=1 means `part` is a
// pre-compacted sorted top-16 row table (no in-conv merge).
template<int C, int O, int QB, int KC, int NB>
__device__ void conv_dev(const float* __restrict__ fsrc, int Nsrc,
    const int* __restrict__ qmap, int Nq, const u64* __restrict__ part,
    const float* __restrict__ w, float* __restrict__ ym, float* __restrict__ yn,
    double2* __restrict__ pp1, char* sm, int bid) {
  constexpr int Og = O / 4;
  constexpr int C4 = C / 4;
  double* rs  = (double*)sm;                    // [256]
  double* rs2 = rs + 256;                       // [256]
  float* ft   = (float*)(sm + 4096);            // [QB][KNN][C]
  float* fqs  = ft + QB*KNN*C;                  // [QB][C]
  int* s_idx  = (int*)(fqs + QB*C);             // [QB][KNN]
  int tid = threadIdx.x;
  int chunk = bid % NB;
  int b = bid / NB;
  int q0 = chunk * QB;
  if (tid < QB) {
    int q = q0 + tid;
    int sq = qmap ? qmap[b*Nq + q] : q;
    const u64* p = part + ((size_t)b*Nsrc + sq)*KC*KNN;
    u64 R[16];
    merge_row<KC>(p, R);
#pragma unroll
    for (int s = 0; s < 16; ++s) s_idx[tid*KNN + s] = (int)(unsigned)(R[s] & 0xFFFFFFFFu);
  } else if (tid >= 64 && tid < 64 + QB*C4) {
    int t = tid - 64;
    int ql = t / C4, c4 = t % C4;
    int q = q0 + ql;
    int sq = qmap ? qmap[b*Nq + q] : q;
    ((float4*)&fqs[ql*C])[c4] = ((const float4*)(fsrc + ((size_t)b*Nsrc + sq)*C))[c4];
  }
  __syncthreads();
  for (int v = tid; v < QB*KNN*C4; v += 256) {
    int row = v / C4, c4 = v % C4;
    int ql = row / KNN, k = row % KNN;
    int src = s_idx[ql*KNN + k];
    ((float4*)&ft[(ql*KNN + k)*C])[c4] = ((const float4*)(fsrc + (size_t)(b*Nsrc + src)*C))[c4];
  }
  __syncthreads();
  int ql = tid / O, o = tid % O;
  float4 wr4[C4];
  float bs = 0.f;
  const float4* wp4 = (const float4*)(w + (size_t)o*2*C);
#pragma unroll
  for (int c4 = 0; c4 < C4; ++c4) {
    float4 lo = wp4[c4], hi = wp4[C4 + c4];
    float4 fv = ((const float4*)&fqs[ql*C])[c4];
    bs += (hi.x - lo.x) * fv.x;
    bs += (hi.y - lo.y) * fv.y;
    bs += (hi.z - lo.z) * fv.z;
    bs += (hi.w - lo.w) * fv.w;
    wr4[c4] = lo;
  }
  float mx = -3.4e38f, mn = 3.4e38f;
  double s = 0.0, s2 = 0.0;
  for (int k = 0; k < KNN; ++k) {
    float acc = bs;
    const float4* fv = (const float4*)&ft[(ql*KNN + k)*C];
#pragma unroll
    for (int c4 = 0; c4 < C4; ++c4) {
      float4 v = fv[c4];
      acc += wr4[c4].x*v.x; acc += wr4[c4].y*v.y;
      acc += wr4[c4].z*v.z; acc += wr4[c4].w*v.w;
    }
    mx = fmaxf(mx, acc);
    mn = fminf(mn, acc);
    s += acc;
    s2 += (double)acc * (double)acc;
  }
  size_t oidx = (size_t)(b*Nq + q0 + ql)*O + o;
  ym[oidx] = mx;
  yn[oidx] = mn;
  rs[tid] = s; rs2[tid] = s2;
  __syncthreads();
#pragma unroll
  for (int st = QB/2; st > 0; st >>= 1) {
    if (ql < st) { rs[tid] += rs[tid + st*O]; rs2[tid] += rs2[tid + st*O]; }
    __syncthreads();
  }
#pragma unroll
  for (int st = Og/2; st > 0; st >>= 1) {
    if (tid < O && (o % Og) < st) { rs[tid] += rs[tid + st]; rs2[tid] += rs2[tid + st]; }
    __syncthreads();
  }
  if (tid < O && (o % Og) == 0) {
    int g = o / Og;
    pp1[((size_t)b*NB + chunk)*4 + g] = make_double2(rs[tid], rs2[tid]);
  }
}

// ---------------- device: finalize (GN + lrelu from minmax) ---------------
template<int O, int NB, int FCH, int NQ>
__device__ void fin_dev(const float* __restrict__ ym, const float* __restrict__ yn,
    const double2* __restrict__ pp1, const float* __restrict__ gamma,
    const float* __restrict__ beta, float* __restrict__ fout, char* sm, int bid) {
  constexpr int Og = O / 4;
  double* red  = (double*)sm;                   // [64]
  double* red2 = red + 64;                      // [64]
  float* s_mu  = (float*)(red2 + 64);           // [4]
  float* s_rsv = s_mu + 4;                      // [4]
  int tid = threadIdx.x;
  int b = bid / FCH;
  int f = bid % FCH;
  if (tid < 64) {
    int g = tid >> 4, j = tid & 15;
    double s = 0.0, s2 = 0.0;
    for (int c = j; c < NB; c += 16) {
      double2 v = pp1[((size_t)b*NB + c)*4 + g];
      s += v.x; s2 += v.y;
    }
    red[tid] = s; red2[tid] = s2;
  }
  __syncthreads();
#pragma unroll
  for (int st = 8; st > 0; st >>= 1) {
    if (tid < 64 && (tid & 15) < st) { red[tid] += red[tid+st]; red2[tid] += red2[tid+st]; }
    __syncthreads();
  }
  if (tid < 4) {
    double cnt = (double)Og * (double)NQ * (double)KNN;
    double mu = red[tid*16] / cnt;
    double var = red2[tid*16] / cnt - mu*mu;
    s_mu[tid] = (float)mu;
    s_rsv[tid] = 1.0f / sqrtf((float)var + EPSV);
  }
  __syncthreads();
  constexpr int PER = NQ * O / FCH;
  int e0 = f * PER;
  for (int e = e0 + tid; e < e0 + PER; e += 256) {
    int q = e / O, o = e % O;
    int g = o / Og;
    size_t idx = (size_t)(b*NQ + q)*O + o;
    float ga = gamma[o], be = beta[o];
    float ysel = (ga >= 0.f) ? ym[idx] : yn[idx];
    float xn = (ysel - s_mu[g]) * s_rsv[g];
    float yv = xn*ga + be;
    yv = yv > 0.f ? yv : LEAK*yv;
    fout[idx] = yv;
  }
}

// ---------------- dispatch wrappers (dynamic shared) ----------------------
__global__ __launch_bounds__(256) void fusedA_kernel(const float* __restrict__ x,
    const float* __restrict__ w_in, const float* __restrict__ b_in,
    float* __restrict__ f0, u64* __restrict__ part, int* __restrict__ fidx1,
    float* __restrict__ g_dl, int* __restrict__ g_far) {
  extern __shared__ char sm[];
  int bid = blockIdx.x;
  if (bid < 16)        fps_seg_dev<8,true>(x, 512, 0, 280, fidx1, g_dl, g_far, nullptr, sm, bid);
  else if (bid < 1040) knn_part_dev(x, 2048, x, 2048, 8, part, sm, bid - 16);
  else                 f0_dev(x, w_in, b_in, f0, bid - 1040);
}

// conv1 dispatch also carries compact1 (part1 -> idx1c) under the fps slack.
__global__ __launch_bounds__(256) void conv1_kernel(const float* __restrict__ x,
    int* __restrict__ fidx1, float* __restrict__ g_dl, int* __restrict__ g_far,
    const float* __restrict__ f0, const u64* __restrict__ part,
    u64* __restrict__ idx1c, const float* __restrict__ w1,
    float* __restrict__ ym, float* __restrict__ yn, double2* __restrict__ pp1) {
  extern __shared__ char sm[];
  int bid = blockIdx.x;
  if (bid < 16)        fps_seg_dev<8,true>(x, 512, 280, 460, fidx1, g_dl, g_far, nullptr, sm, bid);
  else if (bid < 4112) conv_dev<8,32,8,8,256>(f0, 2048, nullptr, 2048, part, w1, ym, yn, pp1, sm, bid - 16);
  else                 compact_dev(part, idx1c, 16*2048, bid - 4112);
}

__global__ __launch_bounds__(256) void fin1_kernel(const float* __restrict__ x,
    int* __restrict__ fidx1, float* __restrict__ g_dl, int* __restrict__ g_far,
    float* __restrict__ cq1,
    const float* __restrict__ ym, const float* __restrict__ yn,
    const double2* __restrict__ pp1, const float* __restrict__ g1,
    const float* __restrict__ be1, float* __restrict__ f1) {
  extern __shared__ char sm[];
  int bid = blockIdx.x;
  if (bid < 16) fps_seg_dev<8,false>(x, 512, 460, 512, fidx1, g_dl, g_far, cq1, sm, bid);
  else          fin_dev<32,256,32,2048>(ym, yn, pp1, g1, be1, f1, sm, bid - 16);
}

// conv2 dispatch carries fps2 (full 128 steps) and knn3.
__global__ __launch_bounds__(256) void conv2_kernel(const float* __restrict__ cq1,
    int* __restrict__ fidx2, float* __restrict__ cq2, u64* __restrict__ part3,
    const float* __restrict__ f1, const int* __restrict__ fidx1,
    const u64* __restrict__ idx1c, const float* __restrict__ w2,
    float* __restrict__ ym, float* __restrict__ yn, double2* __restrict__ pp1) {
  extern __shared__ char sm[];
  int bid = blockIdx.x;
  if (bid < 16) {
    if (threadIdx.x < 64)
      fps2_wave_dev<8>(cq1, 128, fidx2, cq2, sm, bid);
  } else if (bid < 272) {
    knn_part_dev(cq1, 512, cq1, 512, 8, part3, sm, bid - 16);
  } else {
    conv_dev<32,64,4,1,128>(f1, 2048, fidx1, 512, idx1c, w2, ym, yn, pp1, sm, bid - 272);
  }
}

// fin2 dispatch also carries compact3 (part3 -> idx3c).
__global__ __launch_bounds__(256) void fin2_kernel(const float* __restrict__ ym,
    const float* __restrict__ yn, const double2* __restrict__ pp1,
    const float* __restrict__ g2, const float* __restrict__ be2,
    float* __restrict__ f2, const u64* __restrict__ part3, u64* __restrict__ idx3c) {
  extern __shared__ char sm[];
  int bid = blockIdx.x;
  if (bid < 256) fin_dev<64,128,16,512>(ym, yn, pp1, g2, be2, f2, sm, bid);
  else           compact_dev(part3, idx3c, 16*512, bid - 256);
}

__global__ __launch_bounds__(256) void conv3_kernel(const float* __restrict__ f2,
    const u64* __restrict__ idx3c, const float* __restrict__ w3,
    float* __restrict__ ym, float* __restrict__ yn, double2* __restrict__ pp1) {
  extern __shared__ char sm[];
  conv_dev<64,64,4,1,128>(f2, 512, nullptr, 512, idx3c, w3, ym, yn, pp1, sm, blockIdx.x);
}

__global__ __launch_bounds__(256) void fin3_kernel(const float* __restrict__ ym,
    const float* __restrict__ yn, const double2* __restrict__ pp1,
    const float* __restrict__ g3, const float* __restrict__ be3,
    float* __restrict__ f3) {
  extern __shared__ char sm[];
  fin_dev<64,128,16,512>(ym, yn, pp1, g3, be3, f3, sm, blockIdx.x);
}

__global__ __launch_bounds__(256) void conv4_kernel(const float* __restrict__ f3,
    const int* __restrict__ fidx2, const u64* __restrict__ idx3c,
    const float* __restrict__ w4, float* __restrict__ ym, float* __restrict__ yn,
    double2* __restrict__ pp1) {
  extern __shared__ char sm[];
  conv_dev<64,128,2,1,64>(f3, 512, fidx2, 128, idx3c, w4, ym, yn, pp1, sm, blockIdx.x);
}

__global__ __launch_bounds__(256) void fin4_kernel(const float* __restrict__ ym,
    const float* __restrict__ yn, const double2* __restrict__ pp1,
    const float* __restrict__ g4, const float* __restrict__ be4,
    float* __restrict__ f4) {
  extern __shared__ char sm[];
  fin_dev<128,64,8,128>(ym, yn, pp1, g4, be4, f4, sm, blockIdx.x);
}

extern "C" void kernel_launch(void* const* d_in, const int* in_sizes, int n_in,
                              void* d_out, int out_size, void* d_ws, size_t ws_size,
                              hipStream_t stream) {
  const float* x    = (const float*)d_in[0];
  const float* w_in = (const float*)d_in[3];
  const float* b_in = (const float*)d_in[4];
  const float* w1 = (const float*)d_in[5];
  const float* g1 = (const float*)d_in[6];
  const float* be1= (const float*)d_in[7];
  const float* w2 = (const float*)d_in[8];
  const float* g2 = (const float*)d_in[9];
  const float* be2= (const float*)d_in[10];
  const float* w3 = (const float*)d_in[11];
  const float* g3 = (const float*)d_in[12];
  const float* be3= (const float*)d_in[13];
  const float* w4 = (const float*)d_in[14];
  const float* g4 = (const float*)d_in[15];
  const float* be4= (const float*)d_in[16];
  float* out = (float*)d_out;
  (void)in_sizes; (void)n_in; (void)out_size; (void)ws_size;

  char* ws = (char*)d_ws;
  size_t off = 0;
  auto alloc = [&](size_t count) {        // count in 4-byte units
    void* p = ws + off;
    off += (count * 4 + 255) & ~(size_t)255;
    return p;
  };
  float* f0    = (float*)alloc(16*2048*8);
  float* f1    = (float*)alloc(16*2048*32);
  float* f2    = (float*)alloc(16*512*64);
  float* f3    = (float*)alloc(16*512*64);
  float* cq1   = (float*)alloc(16*512*3);
  float* ym    = (float*)alloc(16*2048*32);
  float* yn    = (float*)alloc(16*2048*32);
  double2* pp1 = (double2*)alloc(16*256*4*4);
  int* fidx1   = (int*)alloc(16*512);
  int* fidx2   = (int*)alloc(16*128);
  float* g_dl1 = (float*)alloc(16*2048);
  int* g_far1  = (int*)alloc(16);
  u64* part1 = (u64*)alloc((size_t)2 * 16*2048*8*16);   // 33.5 MB (knn1)
  u64* part3 = (u64*)alloc((size_t)2 * 16*512*8*16);    // 8.4 MB (knn3)
  u64* idx1c = (u64*)alloc((size_t)2 * 16*2048*16);     // 4 MB compacted top-16
  u64* idx3c = (u64*)alloc((size_t)2 * 16*512*16);      // 1 MB

  float* cq2 = out;              // (16,128,3)
  float* f4  = out + 16*128*3;   // (16,128,128)

  // dynamic-LDS sizes (union of branch needs, per kernel)
  constexpr size_t SM_F1  = 2048*16 + 2048 + 64;    // fps1 (4-wave P=8): 34880
  constexpr size_t SM_F2W = 512;                    // fps2 single-wave: s_fid only
  constexpr size_t SM_KNN = 4096;                   // KC=8 -> 256 keys staged
  constexpr size_t SM_C1  = 4096 + 8*KNN*8*4 + 8*8*4 + 8*KNN*4;       // 8960
  constexpr size_t SM_C2  = 4096 + 4*KNN*32*4 + 4*32*4 + 4*KNN*4;     // 13056
  constexpr size_t SM_C3  = 4096 + 4*KNN*64*4 + 4*64*4 + 4*KNN*4;     // 21760
  constexpr size_t SM_C4  = 4096 + 2*KNN*64*4 + 2*64*4 + 2*KNN*4;     // 12928
  constexpr size_t SM_FIN = 1056;
  auto mx2 = [](size_t a, size_t b) { return a > b ? a : b; };
  auto mx3 = [&](size_t a, size_t b, size_t c) { return mx2(a, mx2(b, c)); };

  // L1: knn1(KC=8, 1024 blocks) + f0, fps1[0,280)
  fusedA_kernel<<<1168, 256, mx2(SM_F1, SM_KNN), stream>>>(x, w_in, b_in, f0, part1, fidx1, g_dl1, g_far1);
  // L1 conv + fps1[280,460) + compact1 (rides fps slack)
  conv1_kernel<<<4240, 256, mx2(SM_F1, SM_C1), stream>>>(x, fidx1, g_dl1, g_far1, f0, part1, idx1c, w1, ym, yn, pp1);
  // L1 fin + fps1[460,512) -> cq1
  fin1_kernel<<<528, 256, mx2(SM_F1, SM_FIN), stream>>>(x, fidx1, g_dl1, g_far1, cq1, ym, yn, pp1, g1, be1, f1);

  // L2 conv (rows = idx1c at fidx1, no merge) + fps2 full + knn3
  conv2_kernel<<<2320, 256, mx3(SM_F2W, SM_KNN, SM_C2), stream>>>(cq1, fidx2, cq2, part3,
      f1, fidx1, idx1c, w2, ym, yn, pp1);
  // L2 fin + compact3
  fin2_kernel<<<288, 256, SM_FIN, stream>>>(ym, yn, pp1, g2, be2, f2, part3, idx3c);

  // L3 conv (idx3c direct, no merge)
  conv3_kernel<<<2048, 256, SM_C3, stream>>>(f2, idx3c, w3, ym, yn, pp1);
  fin3_kernel<<<256, 256, SM_FIN, stream>>>(ym, yn, pp1, g3, be3, f3);

  // L4 conv (rows = idx3c at fidx2, no merge)
  conv4_kernel<<<1024, 256, SM_C4, stream>>>(f3, fidx2, idx3c, w4, ym, yn, pp1);
  fin4_kernel<<<128, 256, SM_FIN, stream>>>(ym, yn, pp1, g4, be4, f4);
}